// Round 7
// baseline (26810.974 us; speedup 1.0000x reference)
//
#include <hip/hip_runtime.h>
#include <math.h>

#define Bsz 64
#define Tt  1024
#define TH  512      // entities/slices < T/2, lens >= T/2 -> enc only needed for t < 512

__device__ __forceinline__ float sigm(float x) { return 1.0f / (1.0f + expf(-x)); }

#define GLOAD16(g,l) __builtin_amdgcn_global_load_lds( \
    (const __attribute__((address_space(1))) void*)(g), \
    (__attribute__((address_space(3))) void*)(l), 16, 0, 0)
#define VM8 asm volatile("s_waitcnt vmcnt(8)":::"memory")
#define VM0 asm volatile("s_waitcnt vmcnt(0)":::"memory")
#define LG0 asm volatile("s_waitcnt lgkmcnt(0)":::"memory")
#define BAR __builtin_amdgcn_s_barrier

__device__ __forceinline__ void fma2(const float4 w, const float4 a, const float4 b,
                                     float& s0, float& s1) {
    s0 = fmaf(w.x, a.x, fmaf(w.y, a.z, fmaf(w.z, b.x, fmaf(w.w, b.z, s0))));
    s1 = fmaf(w.x, a.y, fmaf(w.y, a.w, fmaf(w.z, b.y, fmaf(w.w, b.w, s1))));
}

// Pack weights into per-(dir, q-slice, wave) consumption-ordered f4 streams.
// Region (d,q,w): 16 units x 256 f4. Unit layout: pos = k4r*64 + c (4 k4-rows x 64 cols).
// Units 0-1: Q (k4 = 8w+4u+k4r, col = 64q+c), 2-3: R, 4-15: GRU (mat=w>>2, ks4=w&3,
//   g=(u-4)>>2, sub=(u-4)&3, k4 = 16ks4+4sub+k4r, outrow = g*256+64q+c).
__global__ void pack_k(const float* __restrict__ Q, const float* __restrict__ R,
                       const float* __restrict__ Wih_f, const float* __restrict__ Whh_f,
                       const float* __restrict__ Wih_b, const float* __restrict__ Whh_b,
                       float4* __restrict__ Ws)
{
    int fi = blockIdx.x * 256 + threadIdx.x;     // f4 index, 262144 total
    if (fi >= 262144) return;
    int pos = fi & 255, c = pos & 63, k4r = pos >> 6;
    int u = (fi >> 8) & 15;
    int w = (fi >> 12) & 7;
    int q = (fi >> 15) & 3;
    int d = fi >> 17;
    int colg = q * 64 + c;
    float4 v;
    if (u < 4) {
        int uu = u & 1;
        int k4 = 8 * w + 4 * uu + k4r;
        const float* S = ((u >= 2) ? R : Q) + d * 65536;
        v = make_float4(S[(4*k4+0)*256 + colg], S[(4*k4+1)*256 + colg],
                        S[(4*k4+2)*256 + colg], S[(4*k4+3)*256 + colg]);
    } else {
        int mat = w >> 2, ks4 = w & 3;
        int g = (u - 4) >> 2, sub = (u - 4) & 3;
        int k4 = 16 * ks4 + 4 * sub + k4r;
        const float* W = mat ? (d ? Whh_b : Whh_f) : (d ? Wih_b : Wih_f);
        v = *(const float4*)(W + (g * 256 + colg) * 256 + 4 * k4);
    }
    Ws[fi] = v;
}

// Column-parallel scan: 256 WGs = 64 clusters(dir,pair) x 4 col-slices.
// Each WG streams only its 64-col weight slice (640KB/step) via a continuous
// 4-slot global_load_lds ring; cluster exchanges activations through agent-scope
// atomics + per-phase monotonic flag counters (1 polling thread per WG).
__global__ __launch_bounds__(512) void scan_k(
    const int* __restrict__ sents, const int* __restrict__ lens,
    const float* __restrict__ emb,
    const float* __restrict__ bih_f, const float* __restrict__ bhh_f,
    const float* __restrict__ bih_b, const float* __restrict__ bhh_b,
    const float4* __restrict__ Ws, float* __restrict__ pub,
    int* __restrict__ flags, float* __restrict__ enc)
{
    extern __shared__ float sm[];
    float* xs    = sm;            // [256 cols][2 b]
    float* hcs   = sm + 512;
    float* hms   = sm + 1024;
    float* PARTS = sm + 1536;     // 3072 floats (mog 8x128 / gru 24x128 overlay)
    float* DMA   = sm + 4608;     // 8 waves x 4 slots x 1024 floats

    const int bx  = blockIdx.x;
    const int xcd = bx & 7, rem = bx >> 3;
    const int slot_ = rem >> 2, qq = rem & 3;
    const int dir  = xcd >> 2;                   // XCDs 0-3 fwd, 4-7 bwd (locality only)
    const int pair = (xcd & 3) + 4 * slot_;      // 0..31
    const int b0 = pair * 2;
    const int cluster = dir * 32 + pair;

    const int tid = threadIdx.x;
    const int wv = tid >> 6, ln = tid & 63;
    const int cl = tid & 63, cb = (tid >> 6) & 1;   // finalize (tid<128): col, batch
    const int ciL = cl * 2 + cb;
    const int colg = qq * 64 + cl;
    const int ci2 = colg * 2 + cb;
    const int matE = wv >> 2, ks4 = wv & 3;

    float* wbuf = DMA + wv * 4096;
    const float4* Wsb = Ws + (((dir * 4 + qq) * 8 + wv) << 12);
    float* pubC = pub + cluster * 2560;          // 5 phases x 512
    int*   flg  = flags + cluster * 5;
    const float* bih = dir ? bih_b : bih_f;
    const float* bhh = dir ? bhh_b : bhh_f;

    const int len0 = lens[b0], len1 = lens[b0 + 1];
    const int lenE = cb ? len1 : len0;
    const float bi_r = bih[colg], bi_z = bih[colg + 256], bi_n = bih[colg + 512];
    const float bh_r = bhh[colg], bh_z = bhh[colg + 256], bh_n = bhh[colg + 512];

    int t, tstep, nsteps;
    if (!dir) { t = 0; tstep = 1; nsteps = TH; }
    else { int mx = max(len0, len1); t = mx - 1; tstep = -1; nsteps = mx; }

    const int NXT[20] = {3,0,1,2,3,4,5,6,7,8,9,10,11,12,13,14,15,0,1,2};

    const float4* xsLv  = (const float4*)xs;
    const float4* hcsLv = (const float4*)hcs;
    const float4* hmsLv = (const float4*)hms;

    #define ISSUE_UNIT(U, S) do { \
        const float4* gg = Wsb + ((U) << 8) + ln; \
        float* lp = wbuf + (S) * 1024; \
        GLOAD16(gg, lp); GLOAD16(gg + 64, lp + 256); \
        GLOAD16(gg + 128, lp + 512); GLOAD16(gg + 192, lp + 768); \
    } while (0)

    #define CONSUME(K, K4GB, LV, A0, A1) do { \
        VM8; \
        const float* bp_ = wbuf + ((K) & 3) * 1024; \
        float4 w0_ = *(const float4*)(bp_ + 4 * ln); \
        float4 w1_ = *(const float4*)(bp_ + 256 + 4 * ln); \
        float4 w2_ = *(const float4*)(bp_ + 512 + 4 * ln); \
        float4 w3_ = *(const float4*)(bp_ + 768 + 4 * ln); \
        float4 p0_ = (LV)[2*(K4GB)+0], p1_ = (LV)[2*(K4GB)+1]; \
        float4 p2_ = (LV)[2*(K4GB)+2], p3_ = (LV)[2*(K4GB)+3]; \
        float4 p4_ = (LV)[2*(K4GB)+4], p5_ = (LV)[2*(K4GB)+5]; \
        float4 p6_ = (LV)[2*(K4GB)+6], p7_ = (LV)[2*(K4GB)+7]; \
        LG0; \
        ISSUE_UNIT(NXT[(K)], ((K) + 3) & 3); \
        fma2(w0_, p0_, p1_, A0, A1); fma2(w1_, p2_, p3_, A0, A1); \
        fma2(w2_, p4_, p5_, A0, A1); fma2(w3_, p6_, p7_, A0, A1); \
    } while (0)

    #define MOG_PHASE(P, K0, K1, LVp, OWN, GDST) do { \
        float a0_ = 0.f, a1_ = 0.f; \
        CONSUME(K0, 8 * wv,     LVp, a0_, a1_); \
        CONSUME(K1, 8 * wv + 4, LVp, a0_, a1_); \
        PARTS[wv * 128 + 2 * ln]     = a0_; \
        PARTS[wv * 128 + 2 * ln + 1] = a1_; \
        LG0; BAR(); \
        if (tid < 128) { \
            float aa_ = 0.f; \
            _Pragma("unroll") \
            for (int p_ = 0; p_ < 8; ++p_) aa_ += PARTS[p_ * 128 + ciL]; \
            float val_ = 2.f * sigm(aa_) * (OWN); \
            __hip_atomic_store(&pubC[(P) * 512 + ci2], val_, __ATOMIC_RELAXED, __HIP_MEMORY_SCOPE_AGENT); \
        } \
        VM0; BAR(); \
        if (tid == 0) { \
            __hip_atomic_fetch_add(&flg[(P)], 1, __ATOMIC_RELEASE, __HIP_MEMORY_SCOPE_AGENT); \
            int tgt_ = 4 * (s + 1); \
            while (__hip_atomic_load(&flg[(P)], __ATOMIC_ACQUIRE, __HIP_MEMORY_SCOPE_AGENT) < tgt_) \
                __builtin_amdgcn_s_sleep(2); \
        } \
        BAR(); \
        (GDST)[tid] = __hip_atomic_load(&pubC[(P) * 512 + tid], __ATOMIC_RELAXED, __HIP_MEMORY_SCOPE_AGENT); \
        LG0; BAR(); \
    } while (0)

    // prologue
    hcs[tid] = 0.f;
    ISSUE_UNIT(0, 0); ISSUE_UNIT(1, 1); ISSUE_UNIT(2, 2);
    LG0; BAR();

    for (int s = 0; s < nsteps; ++s, t += tstep) {
        float x0 = 0.f;
        if (tid < 128) {
            int tokc = sents[(b0 + cb) * Tt + t];
            x0 = emb[(size_t)tokc * 256 + colg];
        }
        if (s > 0) {   // gather h(s-1) from pubE
            if (tid == 0) {
                int tgt = 4 * s;
                while (__hip_atomic_load(&flg[4], __ATOMIC_ACQUIRE, __HIP_MEMORY_SCOPE_AGENT) < tgt)
                    __builtin_amdgcn_s_sleep(2);
            }
            BAR();
            hcs[tid] = __hip_atomic_load(&pubC[4 * 512 + tid], __ATOMIC_RELAXED, __HIP_MEMORY_SCOPE_AGENT);
            LG0; BAR();
        }

        MOG_PHASE(0, 0, 1, hcsLv, x0,        xs);    // A: x1 = 2sig(h@Q)*x0
        MOG_PHASE(1, 2, 3, xsLv,  hcs[ci2],  hms);   // B: hm1 = 2sig(x1@R)*h
        MOG_PHASE(2, 4, 5, hmsLv, xs[ci2],   xs);    // C: x2 = 2sig(hm1@Q)*x1
        MOG_PHASE(3, 6, 7, xsLv,  hms[ci2],  hms);   // D: hm2 = 2sig(x2@R)*hm1

        // E: GRU (units 8..19)
        {
            const float4* LvE = matE ? hmsLv : xsLv;
            const int gbase = (matE * 4 + ks4) * 384;
            #pragma unroll
            for (int g = 0; g < 3; ++g) {
                float a0_ = 0.f, a1_ = 0.f;
                CONSUME(8 + 4 * g + 0, 16 * ks4 + 0,  LvE, a0_, a1_);
                CONSUME(8 + 4 * g + 1, 16 * ks4 + 4,  LvE, a0_, a1_);
                CONSUME(8 + 4 * g + 2, 16 * ks4 + 8,  LvE, a0_, a1_);
                CONSUME(8 + 4 * g + 3, 16 * ks4 + 12, LvE, a0_, a1_);
                PARTS[gbase + g * 128 + 2 * ln]     = a0_;
                PARTS[gbase + g * 128 + 2 * ln + 1] = a1_;
            }
            LG0; BAR();
            if (tid < 128) {
                float gi[3] = {0.f, 0.f, 0.f}, gh[3] = {0.f, 0.f, 0.f};
                #pragma unroll
                for (int p2 = 0; p2 < 4; ++p2) {
                    #pragma unroll
                    for (int g = 0; g < 3; ++g) {
                        gi[g] += PARTS[(p2 * 3 + g) * 128 + ciL];
                        gh[g] += PARTS[((4 + p2) * 3 + g) * 128 + ciL];
                    }
                }
                float r = sigm(gi[0] + bi_r + gh[0] + bh_r);
                float z = sigm(gi[1] + bi_z + gh[1] + bh_z);
                float n = tanhf(gi[2] + bi_n + r * (gh[2] + bh_n));
                float hm2o = hms[ci2], hso = hcs[ci2];
                float u_ = (1.f - z) * n + z * hm2o;
                bool m = (t < lenE);
                float hnew = m ? u_ : hso;
                __hip_atomic_store(&pubC[4 * 512 + ci2], hnew, __ATOMIC_RELAXED, __HIP_MEMORY_SCOPE_AGENT);
                if (t < TH)
                    atomicAdd(&enc[((size_t)(b0 + cb) * TH + t) * 256 + colg], m ? u_ : 0.f);
            }
            VM0; BAR();
            if (tid == 0)
                __hip_atomic_fetch_add(&flg[4], 1, __ATOMIC_RELEASE, __HIP_MEMORY_SCOPE_AGENT);
        }
    }
    VM0;
    #undef MOG_PHASE
    #undef CONSUME
    #undef ISSUE_UNIT
}

// One WG per batch element. Reproduces gate_attention + attention + dense exactly.
__global__ __launch_bounds__(256) void epi_k(
    const float* __restrict__ enc,
    const int* __restrict__ entities, const int* __restrict__ slices,
    const float* __restrict__ slice_lens,
    const int* __restrict__ entity_masks, const int* __restrict__ slice_masks,
    const float* __restrict__ ent_W, const float* __restrict__ ent_b,
    const float* __restrict__ att_w,
    const float* __restrict__ dense_W, const float* __restrict__ dense_b,
    float* __restrict__ out)
{
    const int b = blockIdx.x;
    const int j = threadIdx.x;
    const int wave = j >> 6, lane = j & 63;

    __shared__ float ee[8][256];
    __shared__ float p[256];
    __shared__ float rela[256];
    __shared__ float sc[264];
    __shared__ float red[4];
    __shared__ float aw[256];
    __shared__ int   spos[256];

    aw[j]   = att_w[j];
    spos[j] = slices[b * 256 + j];
    #pragma unroll
    for (int e = 0; e < 8; ++e)
        ee[e][j] = enc[((size_t)b * TH + entities[b * 8 + e]) * 256 + j];
    __syncthreads();

    float entWj = ent_W[j];
    for (int e = 0; e < 8; ++e) {
        float v = ee[e][j] * entWj;
        #pragma unroll
        for (int o = 32; o > 0; o >>= 1) v += __shfl_down(v, o);
        if (lane == 0) red[wave] = v;
        __syncthreads();
        if (j == 0) sc[e] = red[0] + red[1] + red[2] + red[3] + ent_b[0];
        __syncthreads();
    }
    float mx = -INFINITY;
    float ewv[8];
    #pragma unroll
    for (int e = 0; e < 8; ++e) {
        float v = entity_masks[b * 8 + e] ? sc[e] : -INFINITY;
        ewv[e] = v; mx = fmaxf(mx, v);
    }
    float den = 0.f;
    #pragma unroll
    for (int e = 0; e < 8; ++e) {
        ewv[e] = entity_masks[b * 8 + e] ? expf(ewv[e] - mx) : 0.f;
        den += ewv[e];
    }
    float accp = 0.f;
    #pragma unroll
    for (int e = 0; e < 8; ++e) accp += (ewv[e] / den) * ee[e][j];
    p[j] = tanhf(accp);
    __syncthreads();

    for (int s0 = wave; s0 < 256; s0 += 4) {
        const float* row = enc + ((size_t)b * TH + spos[s0]) * 256;
        float v = 0.f;
        #pragma unroll
        for (int i = 0; i < 4; ++i) { int c = lane + 64 * i; v += row[c] * p[c]; }
        #pragma unroll
        for (int o = 32; o > 0; o >>= 1) v += __shfl_down(v, o);
        if (lane == 0) sc[s0] = v;
    }
    __syncthreads();

    float sl  = slice_lens[b];
    int   smk = slice_masks[b * 256 + j];
    float wv  = smk ? sc[j] : -INFINITY;
    float bm = wv;
    #pragma unroll
    for (int o = 32; o > 0; o >>= 1) bm = fmaxf(bm, __shfl_down(bm, o));
    __syncthreads();
    if (lane == 0) red[wave] = bm;
    __syncthreads();
    bm = fmaxf(fmaxf(red[0], red[1]), fmaxf(red[2], red[3]));
    float ex = smk ? expf(wv - bm) : 0.f;
    float sm2 = ex;
    #pragma unroll
    for (int o = 32; o > 0; o >>= 1) sm2 += __shfl_down(sm2, o);
    __syncthreads();
    if (lane == 0) red[wave] = sm2;
    __syncthreads();
    sm2 = red[0] + red[1] + red[2] + red[3];
    float ww = ex / sm2 * sl;
    float rl = (ww > 0.05f) ? (ww / sl) : 0.f;   // BETA = 0.05
    float rm = rl;
    #pragma unroll
    for (int o = 32; o > 0; o >>= 1) rm = fmaxf(rm, __shfl_down(rm, o));
    __syncthreads();
    if (lane == 0) red[wave] = rm;
    __syncthreads();
    rm = fmaxf(fmaxf(red[0], red[1]), fmaxf(red[2], red[3]));
    rl = rl / rm;
    rela[j] = rl;
    __syncthreads();

    for (int n = wave; n < 264; n += 4) {
        float v = 0.f;
        if (n < 8) {
            #pragma unroll
            for (int i = 0; i < 4; ++i) { int c = lane + 64 * i; v += tanhf(ee[n][c]) * aw[c]; }
        } else {
            int s0 = n - 8;
            const float* row = enc + ((size_t)b * TH + spos[s0]) * 256;
            float rl2 = rela[s0];
            #pragma unroll
            for (int i = 0; i < 4; ++i) { int c = lane + 64 * i; v += tanhf(rl2 * row[c]) * aw[c]; }
        }
        #pragma unroll
        for (int o = 32; o > 0; o >>= 1) v += __shfl_down(v, o);
        if (lane == 0) sc[n] = v;
    }
    __syncthreads();

    float a1 = sc[j];       a1 = (a1 == 0.f) ? -INFINITY : a1;
    float a2 = (j < 8) ? sc[256 + j] : -INFINITY;
    if (a2 == 0.f) a2 = -INFINITY;
    float am = fmaxf(a1, a2);
    #pragma unroll
    for (int o = 32; o > 0; o >>= 1) am = fmaxf(am, __shfl_down(am, o));
    __syncthreads();
    if (lane == 0) red[wave] = am;
    __syncthreads();
    am = fmaxf(fmaxf(red[0], red[1]), fmaxf(red[2], red[3]));
    float e1 = (a1 == -INFINITY) ? 0.f : expf(a1 - am);
    float e2 = (a2 == -INFINITY) ? 0.f : expf(a2 - am);
    float esum = e1 + e2;
    #pragma unroll
    for (int o = 32; o > 0; o >>= 1) esum += __shfl_down(esum, o);
    __syncthreads();
    if (lane == 0) red[wave] = esum;
    __syncthreads();
    esum = red[0] + red[1] + red[2] + red[3];
    __syncthreads();
    sc[j] = e1 / esum;
    if (j < 8) sc[256 + j] = e2 / esum;
    __syncthreads();

    float att = 0.f;
    #pragma unroll
    for (int n = 0; n < 8; ++n) att += sc[n] * ee[n][j];
    for (int s0 = 0; s0 < 256; ++s0) {
        float scn = sc[8 + s0];
        if (scn > 0.f)
            att += scn * rela[s0] * enc[((size_t)b * TH + spos[s0]) * 256 + j];
    }
    float ta = tanhf(att);

    for (int l = 0; l < 19; ++l) {
        float v = ta * dense_W[l * 256 + j];
        #pragma unroll
        for (int o = 32; o > 0; o >>= 1) v += __shfl_down(v, o);
        __syncthreads();
        if (lane == 0) red[wave] = v;
        __syncthreads();
        if (j == 0) out[b * 19 + l] = red[0] + red[1] + red[2] + red[3] + dense_b[l];
    }
}

extern "C" void kernel_launch(void* const* d_in, const int* in_sizes, int n_in,
                              void* d_out, int out_size, void* d_ws, size_t ws_size,
                              hipStream_t stream) {
    (void)in_sizes; (void)n_in; (void)out_size; (void)ws_size;
    const int*   sents        = (const int*)d_in[0];
    const int*   lens         = (const int*)d_in[1];
    const int*   entities     = (const int*)d_in[2];
    const int*   slices       = (const int*)d_in[3];
    const float* slice_lens   = (const float*)d_in[4];
    const int*   entity_masks = (const int*)d_in[5];
    const int*   slice_masks  = (const int*)d_in[6];
    const float* emb          = (const float*)d_in[7];
    const float* Q            = (const float*)d_in[8];
    const float* R            = (const float*)d_in[9];
    const float* Wih_f        = (const float*)d_in[10];
    const float* Whh_f        = (const float*)d_in[11];
    const float* bih_f        = (const float*)d_in[12];
    const float* bhh_f        = (const float*)d_in[13];
    const float* Wih_b        = (const float*)d_in[14];
    const float* Whh_b        = (const float*)d_in[15];
    const float* bih_b        = (const float*)d_in[16];
    const float* bhh_b        = (const float*)d_in[17];
    const float* ent_W        = (const float*)d_in[18];
    const float* ent_b        = (const float*)d_in[19];
    const float* att_w        = (const float*)d_in[20];
    const float* dense_W      = (const float*)d_in[21];
    const float* dense_b      = (const float*)d_in[22];

    // ws: enc [64][512][256] f32 | Ws 262144 f4 (4MB) | pub 64x2560 f32 | flags 64x5 int
    float*  enc   = (float*)d_ws;
    float4* Ws    = (float4*)(enc + (size_t)Bsz * TH * 256);
    float*  pub   = (float*)(Ws + 262144);
    int*    flags = (int*)(pub + 64 * 2560);

    const int smem_bytes = (1536 + 3072 + 8 * 4 * 1024) * 4;   // 149504 B
    hipFuncSetAttribute(reinterpret_cast<const void*>(scan_k),
                        hipFuncAttributeMaxDynamicSharedMemorySize, smem_bytes);

    hipMemsetAsync(enc, 0, (size_t)Bsz * TH * 256 * sizeof(float), stream);
    hipMemsetAsync(flags, 0, 64 * 5 * sizeof(int), stream);
    pack_k<<<1024, 256, 0, stream>>>(Q, R, Wih_f, Whh_f, Wih_b, Whh_b, Ws);
    scan_k<<<256, 512, smem_bytes, stream>>>(sents, lens, emb,
                                             bih_f, bhh_f, bih_b, bhh_b,
                                             Ws, pub, flags, enc);
    epi_k<<<64, 256, 0, stream>>>(enc, entities, slices, slice_lens,
                                  entity_masks, slice_masks, ent_W, ent_b,
                                  att_w, dense_W, dense_b, (float*)d_out);
}